// Round 4
// baseline (131.541 us; speedup 1.0000x reference)
//
#include <hip/hip_runtime.h>
#include <cstdint>

#define NB 8
#define TS 2048
#define NE 1024
#define HD 64
#define MTOT (NB*TS)

typedef float     f4  __attribute__((ext_vector_type(4)));
typedef short     s8v __attribute__((ext_vector_type(8)));
typedef short     s4v __attribute__((ext_vector_type(4)));
typedef int       i4v __attribute__((ext_vector_type(4)));
typedef _Float16  h8  __attribute__((ext_vector_type(8)));

__device__ __forceinline__ short f2bf(float f) {  // RNE
  union { float f; uint32_t u; } x; x.f = f;
  return (short)((x.u + 0x7FFFu + ((x.u >> 16) & 1u)) >> 16);
}

// pack two fp32 -> (bf16(lo) | bf16(hi)<<16) via +0x8000 round + v_perm byte select
__device__ __forceinline__ int pack2(float lo, float hi) {
  union { float f; uint32_t u; } a, b; a.f = lo; b.f = hi;
  return (int)__builtin_amdgcn_perm(b.u + 0x8000u, a.u + 0x8000u, 0x07060302u);
}

// async global->LDS DMA, 16B/lane; lptr wave-uniform, lane i -> lptr + i*16
__device__ __forceinline__ void gl2lds(const void* gptr, void* lptr) {
  auto g = (const __attribute__((address_space(1))) uint32_t*)gptr;
  auto l = (__attribute__((address_space(3))) uint32_t*)lptr;
  __builtin_amdgcn_global_load_lds(g, l, 16, 0, 0);
}

// barrier that keeps N newest vmem ops in flight (AITER-style, never drain unless N=0)
template <int N>
__device__ __forceinline__ void wait_barrier() {
  asm volatile("s_waitcnt vmcnt(%0) lgkmcnt(0)" :: "n"(N) : "memory");
  __builtin_amdgcn_s_barrier();
}

// per-wave vmem wait, NO barrier (for wave-private LDS buffers)
template <int N>
__device__ __forceinline__ void wave_wait() {
  asm volatile("s_waitcnt vmcnt(%0)" :: "n"(N) : "memory");
}

// ---- kernel 0: W fp32 -> bf16 (q-scale folded). wb [192][1024]: 0-63 q, 64-127 k, 128-191 v
__global__ __launch_bounds__(256) void wconv_kernel(
    const float* __restrict__ Wk, const float* __restrict__ Wq, const float* __restrict__ Wv,
    short* __restrict__ wb)
{
  const int idx = (blockIdx.x * 256 + threadIdx.x) * 4;
  const int p = idx >> 16;
  const int off = idx & 65535;
  const float* W = (p == 0) ? Wq : (p == 1) ? Wk : Wv;
  const float s = (p == 0) ? 0.18033688011112042f : 1.0f; // (1/8)*log2(e)
  const float4 v = *(const float4*)&W[off];
  s4v h; h[0] = f2bf(v.x*s); h[1] = f2bf(v.y*s); h[2] = f2bf(v.z*s); h[3] = f2bf(v.w*s);
  *(s4v*)&wb[idx] = h;
}

// ---- kernel 1: fused qkv projection. grid 512 x 256 thr, tile 32 rows x 192 cols,
// wave = 16 rows x 96 cols. LDS exactly 80 KB -> 2 blocks/CU (8 waves/CU).
// x: 4-buf fp32 DMA (3-ahead issue); W: 2-buf bf16 DMA (1-ahead). XOR slot-swizzle.
__global__ __launch_bounds__(256) void proj_kernel(
    const float* __restrict__ x, const short* __restrict__ wb,
    short* __restrict__ qo, short* __restrict__ ko, _Float16* __restrict__ vo)
{
  __shared__ float Xs[4][32][64];    // 32 KB
  __shared__ short Ws[2][192][64];   // 48 KB
  const int tid = threadIdx.x;
  const int wv = tid >> 6, lane = tid & 63, n = lane & 15, quad = lane >> 4;
  const int mg = wv & 1, cg = wv >> 1;
  const int r0 = blockIdx.x * 32;
  const int xrow = lane >> 4, xslot = lane & 15;   // x DMA: 4 rows x 16 slots (16B fp32)
  const int wrow = lane >> 3, wslot = lane & 7;    // W DMA: 8 cols x 8 slots (16B bf16)

  auto dmaX = [&](int c, int buf) {
#pragma unroll
    for (int u = 0; u < 2; ++u) {
      const int R0 = (wv * 2 + u) * 4;
      const int row = R0 + xrow;
      const int gs = (xslot + row) & 15;
      gl2lds(&x[(size_t)(r0 + row) * NE + c * 64 + gs * 4], &Xs[buf][R0][0]);
    }
  };
  auto dmaW = [&](int c, int buf) {
#pragma unroll
    for (int u = 0; u < 6; ++u) {
      const int C0 = (wv * 6 + u) * 8;
      const int col = C0 + wrow;
      const int gs = (wslot + col) & 7;
      gl2lds(&wb[(size_t)col * NE + c * 64 + gs * 8], &Ws[buf][C0][0]);
    }
  };

  const f4 fz = {0.f, 0.f, 0.f, 0.f};
  f4 acc[6] = {fz, fz, fz, fz, fz, fz};

  auto compute = [&](int bw, int bx) {
    s8v a[2];
    const int row = mg * 16 + n;
#pragma unroll
    for (int kc = 0; kc < 2; ++kc) {
      const int u0 = kc * 8 + quad * 2;
      const float* pr = &Xs[bx][row][0];
      const f4 f0 = *(const f4*)(pr + (((u0    ) - row) & 15) * 4);
      const f4 f1 = *(const f4*)(pr + (((u0 + 1) - row) & 15) * 4);
      i4v ai;
      ai[0] = pack2(f0[0], f0[1]); ai[1] = pack2(f0[2], f0[3]);
      ai[2] = pack2(f1[0], f1[1]); ai[3] = pack2(f1[2], f1[3]);
      a[kc] = __builtin_bit_cast(s8v, ai);
    }
#pragma unroll
    for (int nf = 0; nf < 6; ++nf) {
      const int col = cg * 96 + nf * 16 + n;
      const s8v b0 = *(const s8v*)&Ws[bw][col][(((0 + quad) - col) & 7) * 8];
      const s8v b1 = *(const s8v*)&Ws[bw][col][(((4 + quad) - col) & 7) * 8];
      acc[nf] = __builtin_amdgcn_mfma_f32_16x16x32_bf16(a[0], b0, acc[nf], 0, 0, 0);
      acc[nf] = __builtin_amdgcn_mfma_f32_16x16x32_bf16(a[1], b1, acc[nf], 0, 0, 0);
    }
  };

  // prologue: W0 first, then X0..X2 (FIFO: waiting for X0 keeps X1,X2 in flight)
  dmaW(0, 0); dmaX(0, 0); dmaX(1, 1); dmaX(2, 2);
  wait_barrier<4>();

  for (int t = 0; t < 16; ++t) {
    if (t <= 14) dmaW(t + 1, (t + 1) & 1);   // W first (older in FIFO than this iter's X)
    if (t <= 12) dmaX(t + 3, (t + 3) & 3);
    compute(t & 1, t & 3);
    if (t <= 12)      wait_barrier<2>();     // keep X(t+3) flying; X(t+1),W(t+1) landed
    else if (t <= 14) wait_barrier<0>();     // tail
  }

  // epilogue: C row = quad*4+i, col = n (+16*nf)
#pragma unroll
  for (int nf = 0; nf < 6; ++nf) {
    const int gc = cg * 96 + nf * 16;
    const int p = gc >> 6;
    const int rcol = (gc & 63) + n;
#pragma unroll
    for (int i = 0; i < 4; ++i) {
      const int R = r0 + mg * 16 + quad * 4 + i;
      const float av = acc[nf][i];
      if (p == 0)      qo[(size_t)R * HD + rcol] = f2bf(av);
      else if (p == 1) ko[(size_t)R * HD + rcol] = f2bf(av);
      else {
        // V transposed [b][d][t'] + key-order swizzle so attn PV B-frags are single 16B loads
        const int t2 = R & (TS - 1), b = t2 & 31;
        const int pos = (t2 & ~31) | (((b >> 2) & 3) << 3) | (((b >> 4) & 1) << 2) | (b & 3);
        vo[(size_t)(R >> 11) * HD * TS + (size_t)rcol * TS + pos] = (_Float16)av;
      }
    }
  }
}

// ---- kernel 2: attention. grid 512 x 256 thr (4 waves). 32 q/block.
// Each WAVE owns one key-quarter (512 keys) for ALL 32 q: buffers are wave-private ->
// ZERO main-loop barriers. Chunk = 32 keys; K[4][2][32][64]bf16 + V[4][2][64][32]f16
// = 64 KB -> 2 blocks/CU (8 waves/CU, free-running; block sync only at combine).
// Buffer hand-off is per-wave s_waitcnt vmcnt(0): global_load_lds retirement is tracked
// by the issuing wave's vmcnt, and only that wave reads the LDS it targets.
// Per-unit-work MFMA / LDS-read / DMA-op / exp2 counts identical to R3 (pure sync xform).
// S^T = K Q^T -> exp2 in-reg -> f16 PV; l via P*ones. 4-way combine in LDS overlay.
__global__ __launch_bounds__(256) void attn_kernel(
    const short* __restrict__ q, const short* __restrict__ k,
    const _Float16* __restrict__ vT, float* __restrict__ out)
{
  __shared__ __align__(16) char smem[65536];   // K 32 KB | V 32 KB ; overlay o_c/l_c after
  const int tid = threadIdx.x;
  const int wv = tid >> 6, lane = tid & 63, n = lane & 15, quad = lane >> 4;
  const int kq = wv;                           // wave's key-quarter
  const int batch = blockIdx.x & 7;            // XCD swizzle: batch K/V pinned per XCD L2
  const int qgb = blockIdx.x >> 3;
  const int m0 = batch * TS + qgb * 32;
  const short*    kb = k  + (size_t)batch * TS * HD;
  const _Float16* vb = vT + (size_t)batch * HD * TS;
  const int krow = lane >> 3, kslot = lane & 7;   // K DMA: 8 rows x 8 slots (16B bf16)
  const int vrow = lane >> 2, vslot = lane & 3;   // V DMA: 16 rows x 4 slots (16B f16)
  const f4 fz = {0.f, 0.f, 0.f, 0.f};

  auto kbuf = [&](int buf) { return (short*)   (smem +         (kq * 2 + buf) * 4096); };
  auto vbuf = [&](int buf) { return (_Float16*)(smem + 32768 + (kq * 2 + buf) * 4096); };

  // stage one 32-key K+V chunk (wave-private): 4 K ops (8 rows x 128B) + 4 V ops (16 rows x 64B)
  auto dmaKV = [&](int tt, int buf) {
    const int c = kq * 16 + tt;
#pragma unroll
    for (int u = 0; u < 4; ++u) {
      const int K0 = u * 8;
      const int key = K0 + krow;
      const int gs = (kslot + key) & 7;
      gl2lds(&kb[(size_t)(c * 32 + key) * HD + gs * 8], kbuf(buf) + K0 * 64);
    }
#pragma unroll
    for (int u = 0; u < 4; ++u) {
      const int D0 = u * 16;
      const int d = D0 + vrow;
      const int gs = (vslot + d) & 3;
      gl2lds(&vb[(size_t)d * TS + c * 32 + gs * 8], vbuf(buf) + D0 * 32);
    }
  };

  s8v qf[2][2];
#pragma unroll
  for (int qh = 0; qh < 2; ++qh)
#pragma unroll
    for (int kc = 0; kc < 2; ++kc)
      qf[qh][kc] = *(const s8v*)&q[(size_t)(m0 + qh * 16 + n) * HD + kc * 32 + quad * 8];

  f4 o[2][4] = {{fz, fz, fz, fz}, {fz, fz, fz, fz}};
  f4 lD[2] = {fz, fz};
  h8 ones;
#pragma unroll
  for (int j = 0; j < 8; ++j) ones[j] = (_Float16)1.0f;

  dmaKV(0, 0); dmaKV(1, 1);   // 8 ops each, wave-private
  wave_wait<8>();             // chunk 0 landed; chunk 1's 8 ops in flight

  for (int t = 0; t < 16; ++t) {
    const int buf = t & 1;

    // prefetch chunk t+1 into the buffer this wave consumed at t-1 (WAR-safe: those
    // ds_reads retired before t-1's MFMAs issued; DMA writeback lands much later)
    if (t >= 1 && t <= 14) dmaKV(t + 1, (t + 1) & 1);

    const short*    ks = kbuf(buf);
    const _Float16* vs = vbuf(buf);

    // QK^T: 32 keys x 32 q. Per key-fragment feed both q-groups (short live range)
    f4 st[2][2];
#pragma unroll
    for (int f = 0; f < 2; ++f) {
      const int key = f * 16 + n;
      const s8v k0 = *(const s8v*)&ks[key * 64 + (((0 + quad) - key) & 7) * 8];
      const s8v k1 = *(const s8v*)&ks[key * 64 + (((4 + quad) - key) & 7) * 8];
#pragma unroll
      for (int qh = 0; qh < 2; ++qh) {
        st[qh][f] = __builtin_amdgcn_mfma_f32_16x16x32_bf16(k0, qf[qh][0], fz, 0, 0, 0);
        st[qh][f] = __builtin_amdgcn_mfma_f32_16x16x32_bf16(k1, qf[qh][1], st[qh][f], 0, 0, 0);
      }
    }

    h8 pa[2];
#pragma unroll
    for (int qh = 0; qh < 2; ++qh)
#pragma unroll
      for (int f = 0; f < 2; ++f)
#pragma unroll
        for (int i = 0; i < 4; ++i)
          pa[qh][f * 4 + i] = (_Float16)__builtin_amdgcn_exp2f(st[qh][f][i]);

#pragma unroll
    for (int qh = 0; qh < 2; ++qh)
      lD[qh] = __builtin_amdgcn_mfma_f32_16x16x32_f16(pa[qh], ones, lD[qh], 0, 0, 0);
#pragma unroll
    for (int g = 0; g < 4; ++g) {
      const int d = g * 16 + n;
      const h8 vf = *(const h8*)&vs[d * 32 + ((quad - d) & 3) * 8];
#pragma unroll
      for (int qh = 0; qh < 2; ++qh)
        o[qh][g] = __builtin_amdgcn_mfma_f32_16x16x32_f16(pa[qh], vf, o[qh][g], 0, 0, 0);
    }

    // per-wave wait: chunk t+1 landed (covered by this iter's compute). No barrier.
    if (t <= 14) wave_wait<0>();
  }

  __syncthreads();   // only block-wide sync: all waves done with K/V LDS before overlay

  float* o_c = (float*)smem;              // [4 kq][32 q][68] f32 = 34816 B
  float* l_c = (float*)(smem + 34816);    // [4 kq][32 q]
  if (n == 0)
#pragma unroll
    for (int qh = 0; qh < 2; ++qh)
#pragma unroll
      for (int i = 0; i < 4; ++i)
        l_c[kq * 32 + qh * 16 + quad * 4 + i] = lD[qh][i];
#pragma unroll
  for (int qh = 0; qh < 2; ++qh)
#pragma unroll
    for (int g = 0; g < 4; ++g)
#pragma unroll
      for (int i = 0; i < 4; ++i)
        o_c[kq * 2176 + (qh * 16 + quad * 4 + i) * 68 + g * 16 + n] = o[qh][g][i];
  __syncthreads();

  // combine quarters: 512 output-groups (32 q x 16 d4), 256 thr x 2 reps
#pragma unroll
  for (int rep = 0; rep < 2; ++rep) {
    const int idx = tid + rep * 256;
    const int qr = idx >> 4, d4 = (idx & 15) * 4;
    float L = 0.f;
    f4 r = fz;
#pragma unroll
    for (int c2 = 0; c2 < 4; ++c2) {
      L += l_c[c2 * 32 + qr];
      r += *(const f4*)&o_c[c2 * 2176 + qr * 68 + d4];
    }
    const float inv = 1.0f / L;
    r[0] *= inv; r[1] *= inv; r[2] *= inv; r[3] *= inv;
    *(f4*)&out[(size_t)(m0 + qr) * HD + d4] = r;
  }
}

extern "C" void kernel_launch(void* const* d_in, const int* in_sizes, int n_in,
                              void* d_out, int out_size, void* d_ws, size_t ws_size,
                              hipStream_t stream) {
  const float* x  = (const float*)d_in[0];
  const float* Wk = (const float*)d_in[1];
  const float* Wq = (const float*)d_in[2];
  const float* Wv = (const float*)d_in[3];
  float* out = (float*)d_out;

  short* qb = (short*)d_ws;                           // [MTOT][64] bf16 (pre-scaled)
  short* kb = qb + (size_t)MTOT * HD;                 // [MTOT][64] bf16
  _Float16* vb = (_Float16*)(kb + (size_t)MTOT * HD); // [NB][64][TS] f16, key-swizzled
  short* wb = (short*)(vb + (size_t)NB * HD * TS);    // [192][1024] bf16 weights

  wconv_kernel<<<192, 256, 0, stream>>>(Wk, Wq, Wv, wb);
  proj_kernel<<<MTOT / 32, 256, 0, stream>>>(x, wb, qb, kb, vb);
  attn_kernel<<<MTOT / 32, 256, 0, stream>>>(qb, kb, vb, out);
}

// Round 5
// 128.994 us; speedup vs baseline: 1.0197x; 1.0197x over previous
//
#include <hip/hip_runtime.h>
#include <cstdint>

#define NB 8
#define TS 2048
#define NE 1024
#define HD 64
#define MTOT (NB*TS)

typedef float     f4  __attribute__((ext_vector_type(4)));
typedef short     s8v __attribute__((ext_vector_type(8)));
typedef short     s4v __attribute__((ext_vector_type(4)));
typedef int       i4v __attribute__((ext_vector_type(4)));
typedef _Float16  h8  __attribute__((ext_vector_type(8)));

__device__ __forceinline__ short f2bf(float f) {  // RNE
  union { float f; uint32_t u; } x; x.f = f;
  return (short)((x.u + 0x7FFFu + ((x.u >> 16) & 1u)) >> 16);
}

// pack two fp32 -> (bf16(lo) | bf16(hi)<<16) via +0x8000 round + v_perm byte select
__device__ __forceinline__ int pack2(float lo, float hi) {
  union { float f; uint32_t u; } a, b; a.f = lo; b.f = hi;
  return (int)__builtin_amdgcn_perm(b.u + 0x8000u, a.u + 0x8000u, 0x07060302u);
}

// async global->LDS DMA, 16B/lane; lptr wave-uniform, lane i -> lptr + i*16
__device__ __forceinline__ void gl2lds(const void* gptr, void* lptr) {
  auto g = (const __attribute__((address_space(1))) uint32_t*)gptr;
  auto l = (__attribute__((address_space(3))) uint32_t*)lptr;
  __builtin_amdgcn_global_load_lds(g, l, 16, 0, 0);
}

// barrier that keeps N newest vmem ops in flight (AITER-style, never drain unless N=0)
template <int N>
__device__ __forceinline__ void wait_barrier() {
  asm volatile("s_waitcnt vmcnt(%0) lgkmcnt(0)" :: "n"(N) : "memory");
  __builtin_amdgcn_s_barrier();
}

// per-wave vmem wait, NO barrier (for wave-private LDS buffers)
template <int N>
__device__ __forceinline__ void wave_wait() {
  asm volatile("s_waitcnt vmcnt(%0)" :: "n"(N) : "memory");
}

// ---- kernel 0: W fp32 -> bf16 (q-scale folded). wb [192][1024]: 0-63 q, 64-127 k, 128-191 v
__global__ __launch_bounds__(256) void wconv_kernel(
    const float* __restrict__ Wk, const float* __restrict__ Wq, const float* __restrict__ Wv,
    short* __restrict__ wb)
{
  const int idx = (blockIdx.x * 256 + threadIdx.x) * 4;
  const int p = idx >> 16;
  const int off = idx & 65535;
  const float* W = (p == 0) ? Wq : (p == 1) ? Wk : Wv;
  const float s = (p == 0) ? 0.18033688011112042f : 1.0f; // (1/8)*log2(e)
  const float4 v = *(const float4*)&W[off];
  s4v h; h[0] = f2bf(v.x*s); h[1] = f2bf(v.y*s); h[2] = f2bf(v.z*s); h[3] = f2bf(v.w*s);
  *(s4v*)&wb[idx] = h;
}

// ---- kernel 1: fused qkv projection. grid 512 x 256 thr, tile 32 rows x 192 cols,
// wave = 16 rows x 96 cols. LDS exactly 80 KB -> 2 blocks/CU (8 waves/CU).
// x: 4-buf fp32 DMA (3-ahead issue); W: 2-buf bf16 DMA (1-ahead). XOR slot-swizzle.
__global__ __launch_bounds__(256) void proj_kernel(
    const float* __restrict__ x, const short* __restrict__ wb,
    short* __restrict__ qo, short* __restrict__ ko, _Float16* __restrict__ vo)
{
  __shared__ float Xs[4][32][64];    // 32 KB
  __shared__ short Ws[2][192][64];   // 48 KB
  const int tid = threadIdx.x;
  const int wv = tid >> 6, lane = tid & 63, n = lane & 15, quad = lane >> 4;
  const int mg = wv & 1, cg = wv >> 1;
  const int r0 = blockIdx.x * 32;
  const int xrow = lane >> 4, xslot = lane & 15;   // x DMA: 4 rows x 16 slots (16B fp32)
  const int wrow = lane >> 3, wslot = lane & 7;    // W DMA: 8 cols x 8 slots (16B bf16)

  auto dmaX = [&](int c, int buf) {
#pragma unroll
    for (int u = 0; u < 2; ++u) {
      const int R0 = (wv * 2 + u) * 4;
      const int row = R0 + xrow;
      const int gs = (xslot + row) & 15;
      gl2lds(&x[(size_t)(r0 + row) * NE + c * 64 + gs * 4], &Xs[buf][R0][0]);
    }
  };
  auto dmaW = [&](int c, int buf) {
#pragma unroll
    for (int u = 0; u < 6; ++u) {
      const int C0 = (wv * 6 + u) * 8;
      const int col = C0 + wrow;
      const int gs = (wslot + col) & 7;
      gl2lds(&wb[(size_t)col * NE + c * 64 + gs * 8], &Ws[buf][C0][0]);
    }
  };

  const f4 fz = {0.f, 0.f, 0.f, 0.f};
  f4 acc[6] = {fz, fz, fz, fz, fz, fz};

  auto compute = [&](int bw, int bx) {
    s8v a[2];
    const int row = mg * 16 + n;
#pragma unroll
    for (int kc = 0; kc < 2; ++kc) {
      const int u0 = kc * 8 + quad * 2;
      const float* pr = &Xs[bx][row][0];
      const f4 f0 = *(const f4*)(pr + (((u0    ) - row) & 15) * 4);
      const f4 f1 = *(const f4*)(pr + (((u0 + 1) - row) & 15) * 4);
      i4v ai;
      ai[0] = pack2(f0[0], f0[1]); ai[1] = pack2(f0[2], f0[3]);
      ai[2] = pack2(f1[0], f1[1]); ai[3] = pack2(f1[2], f1[3]);
      a[kc] = __builtin_bit_cast(s8v, ai);
    }
#pragma unroll
    for (int nf = 0; nf < 6; ++nf) {
      const int col = cg * 96 + nf * 16 + n;
      const s8v b0 = *(const s8v*)&Ws[bw][col][(((0 + quad) - col) & 7) * 8];
      const s8v b1 = *(const s8v*)&Ws[bw][col][(((4 + quad) - col) & 7) * 8];
      acc[nf] = __builtin_amdgcn_mfma_f32_16x16x32_bf16(a[0], b0, acc[nf], 0, 0, 0);
      acc[nf] = __builtin_amdgcn_mfma_f32_16x16x32_bf16(a[1], b1, acc[nf], 0, 0, 0);
    }
  };

  // prologue: W0 first, then X0..X2 (FIFO: waiting for X0 keeps X1,X2 in flight)
  dmaW(0, 0); dmaX(0, 0); dmaX(1, 1); dmaX(2, 2);
  wait_barrier<4>();

  for (int t = 0; t < 16; ++t) {
    if (t <= 14) dmaW(t + 1, (t + 1) & 1);   // W first (older in FIFO than this iter's X)
    if (t <= 12) dmaX(t + 3, (t + 3) & 3);
    compute(t & 1, t & 3);
    if (t <= 12)      wait_barrier<2>();     // keep X(t+3) flying; X(t+1),W(t+1) landed
    else if (t <= 14) wait_barrier<0>();     // tail
  }

  // epilogue: C row = quad*4+i, col = n (+16*nf)
#pragma unroll
  for (int nf = 0; nf < 6; ++nf) {
    const int gc = cg * 96 + nf * 16;
    const int p = gc >> 6;
    const int rcol = (gc & 63) + n;
#pragma unroll
    for (int i = 0; i < 4; ++i) {
      const int R = r0 + mg * 16 + quad * 4 + i;
      const float av = acc[nf][i];
      if (p == 0)      qo[(size_t)R * HD + rcol] = f2bf(av);
      else if (p == 1) ko[(size_t)R * HD + rcol] = f2bf(av);
      else {
        // V transposed [b][d][t'] + key-order swizzle so attn PV B-frags are single 16B loads
        const int t2 = R & (TS - 1), b = t2 & 31;
        const int pos = (t2 & ~31) | (((b >> 2) & 3) << 3) | (((b >> 4) & 1) << 2) | (b & 3);
        vo[(size_t)(R >> 11) * HD * TS + (size_t)rcol * TS + pos] = (_Float16)av;
      }
    }
  }
}

// ---- kernel 2: attention. grid 256 x 512 thr (8 waves). 64 q/block (R3's traffic shape:
// each block reads its batch's 512 KB K/V exactly once -> L2 demand stays ~13 TB/s).
// Each WAVE owns one key-EIGHTH (256 keys) and computes ALL 64 q (4 q-frags):
// buffers are wave-private -> ZERO main-loop barriers (R4's sync win without its L2 cost).
// Chunk = 32 keys, 8 iters, 2-buf: K[8][2][32][64]bf16 + V[8][2][64][32]f16 = 128 KB.
// Hand-off = per-wave s_waitcnt vmcnt(0); WAR safe (compiler lgkm-waits before MFMAs
// retire each iter's ds_reads before the next prefetch issues). V-frag MFMA reuse x4.
// st -> pa converted per q-frag to cap live registers (~190 peak).
// S^T = K Q^T -> exp2 in-reg -> f16 PV; l via P*ones. 8-way combine in LDS overlay.
__global__ __launch_bounds__(512, 2) void attn_kernel(
    const short* __restrict__ q, const short* __restrict__ k,
    const _Float16* __restrict__ vT, float* __restrict__ out)
{
  __shared__ __align__(16) char smem[141312];  // main: K 64KB | V 64KB ; overlay: o_c/l_c
  const int tid = threadIdx.x;
  const int wv = tid >> 6, lane = tid & 63, n = lane & 15, quad = lane >> 4;
  const int batch = blockIdx.x & 7;            // XCD swizzle: batch K/V pinned per XCD L2
  const int qgb = blockIdx.x >> 3;
  const int m0 = batch * TS + qgb * 64;
  const short*    kb = k  + (size_t)batch * TS * HD;
  const _Float16* vb = vT + (size_t)batch * HD * TS;
  const int krow = lane >> 3, kslot = lane & 7;   // K DMA: 8 rows x 8 slots (16B bf16)
  const int vrow = lane >> 2, vslot = lane & 3;   // V DMA: 16 rows x 4 slots (16B f16)
  const f4 fz = {0.f, 0.f, 0.f, 0.f};

  auto kbuf = [&](int buf) { return (short*)   (smem +         (wv * 2 + buf) * 4096); };
  auto vbuf = [&](int buf) { return (_Float16*)(smem + 65536 + (wv * 2 + buf) * 4096); };

  // stage one wave-private 32-key K+V chunk: 4 K ops (8 rows x 128B) + 4 V ops (16 rows x 64B)
  auto dmaKV = [&](int tt, int buf) {
    const int c = wv * 8 + tt;                 // wave's key-eighth, chunk tt of 8
#pragma unroll
    for (int u = 0; u < 4; ++u) {
      const int K0 = u * 8;
      const int key = K0 + krow;
      const int gs = (kslot + key) & 7;
      gl2lds(&kb[(size_t)(c * 32 + key) * HD + gs * 8], kbuf(buf) + K0 * 64);
    }
#pragma unroll
    for (int u = 0; u < 4; ++u) {
      const int D0 = u * 16;
      const int d = D0 + vrow;
      const int gs = (vslot + d) & 3;
      gl2lds(&vb[(size_t)d * TS + c * 32 + gs * 8], vbuf(buf) + D0 * 32);
    }
  };

  s8v qf[4][2];
#pragma unroll
  for (int qh = 0; qh < 4; ++qh)
#pragma unroll
    for (int kc = 0; kc < 2; ++kc)
      qf[qh][kc] = *(const s8v*)&q[(size_t)(m0 + qh * 16 + n) * HD + kc * 32 + quad * 8];

  f4 o[4][4] = {{fz, fz, fz, fz}, {fz, fz, fz, fz}, {fz, fz, fz, fz}, {fz, fz, fz, fz}};
  f4 lD[4] = {fz, fz, fz, fz};
  h8 ones;
#pragma unroll
  for (int j = 0; j < 8; ++j) ones[j] = (_Float16)1.0f;

  dmaKV(0, 0); dmaKV(1, 1);   // 8 ops each, wave-private
  wave_wait<8>();             // q-frags + chunk 0 landed; chunk 1's 8 ops in flight

  for (int t = 0; t < 8; ++t) {
    const int buf = t & 1;

    // prefetch chunk t+1 into the buffer this wave consumed at t-1 (WAR-safe, see header)
    if (t >= 1 && t <= 6) dmaKV(t + 1, (t + 1) & 1);

    const short*    ks = kbuf(buf);
    const _Float16* vs = vbuf(buf);

    // K fragments once (reused by all 4 q-frags)
    s8v kf[2][2];
#pragma unroll
    for (int f = 0; f < 2; ++f) {
      const int key = f * 16 + n;
      kf[f][0] = *(const s8v*)&ks[key * 64 + (((0 + quad) - key) & 7) * 8];
      kf[f][1] = *(const s8v*)&ks[key * 64 + (((4 + quad) - key) & 7) * 8];
    }

    // per q-frag: QK^T -> exp2 -> pa (st live range = one q-frag)
    h8 pa[4];
#pragma unroll
    for (int qh = 0; qh < 4; ++qh) {
      f4 s0 = __builtin_amdgcn_mfma_f32_16x16x32_bf16(kf[0][0], qf[qh][0], fz, 0, 0, 0);
      s0     = __builtin_amdgcn_mfma_f32_16x16x32_bf16(kf[0][1], qf[qh][1], s0, 0, 0, 0);
      f4 s1 = __builtin_amdgcn_mfma_f32_16x16x32_bf16(kf[1][0], qf[qh][0], fz, 0, 0, 0);
      s1     = __builtin_amdgcn_mfma_f32_16x16x32_bf16(kf[1][1], qf[qh][1], s1, 0, 0, 0);
#pragma unroll
      for (int i = 0; i < 4; ++i) {
        pa[qh][i]     = (_Float16)__builtin_amdgcn_exp2f(s0[i]);
        pa[qh][4 + i] = (_Float16)__builtin_amdgcn_exp2f(s1[i]);
      }
    }

#pragma unroll
    for (int qh = 0; qh < 4; ++qh)
      lD[qh] = __builtin_amdgcn_mfma_f32_16x16x32_f16(pa[qh], ones, lD[qh], 0, 0, 0);
#pragma unroll
    for (int g = 0; g < 4; ++g) {
      const int d = g * 16 + n;
      const h8 vf = *(const h8*)&vs[d * 32 + ((quad - d) & 3) * 8];
#pragma unroll
      for (int qh = 0; qh < 4; ++qh)
        o[qh][g] = __builtin_amdgcn_mfma_f32_16x16x32_f16(pa[qh], vf, o[qh][g], 0, 0, 0);
    }

    // per-wave wait: chunk t+1 landed (covered by this iter's compute). No barrier.
    if (t <= 6) wave_wait<0>();
  }

  __syncthreads();   // only block-wide sync: all waves done with K/V LDS before overlay

  float* o_c = (float*)smem;               // [8 eighth][64 q][68] f32 = 139264 B
  float* l_c = (float*)(smem + 139264);    // [8 eighth][64 q]
  if (n == 0)
#pragma unroll
    for (int qh = 0; qh < 4; ++qh)
#pragma unroll
      for (int i = 0; i < 4; ++i)
        l_c[wv * 64 + qh * 16 + quad * 4 + i] = lD[qh][i];
#pragma unroll
  for (int qh = 0; qh < 4; ++qh)
#pragma unroll
    for (int g = 0; g < 4; ++g)
#pragma unroll
      for (int i = 0; i < 4; ++i)
        o_c[wv * 4352 + (qh * 16 + quad * 4 + i) * 68 + g * 16 + n] = o[qh][g][i];
  __syncthreads();

  // combine eighths: 1024 output-groups (64 q x 16 d4), 512 thr x 2 reps
#pragma unroll
  for (int rep = 0; rep < 2; ++rep) {
    const int idx = tid + rep * 512;
    const int qr = idx >> 4, d4 = (idx & 15) * 4;
    float L = 0.f;
    f4 r = fz;
#pragma unroll
    for (int c2 = 0; c2 < 8; ++c2) {
      L += l_c[c2 * 64 + qr];
      r += *(const f4*)&o_c[c2 * 4352 + qr * 68 + d4];
    }
    const float inv = 1.0f / L;
    r[0] *= inv; r[1] *= inv; r[2] *= inv; r[3] *= inv;
    *(f4*)&out[(size_t)(m0 + qr) * HD + d4] = r;
  }
}

extern "C" void kernel_launch(void* const* d_in, const int* in_sizes, int n_in,
                              void* d_out, int out_size, void* d_ws, size_t ws_size,
                              hipStream_t stream) {
  const float* x  = (const float*)d_in[0];
  const float* Wk = (const float*)d_in[1];
  const float* Wq = (const float*)d_in[2];
  const float* Wv = (const float*)d_in[3];
  float* out = (float*)d_out;

  short* qb = (short*)d_ws;                           // [MTOT][64] bf16 (pre-scaled)
  short* kb = qb + (size_t)MTOT * HD;                 // [MTOT][64] bf16
  _Float16* vb = (_Float16*)(kb + (size_t)MTOT * HD); // [NB][64][TS] f16, key-swizzled
  short* wb = (short*)(vb + (size_t)NB * HD * TS);    // [192][1024] bf16 weights

  wconv_kernel<<<192, 256, 0, stream>>>(Wk, Wq, Wv, wb);
  proj_kernel<<<MTOT / 32, 256, 0, stream>>>(x, wb, qb, kb, vb);
  attn_kernel<<<MTOT / 64, 512, 0, stream>>>(qb, kb, vb, out);
}

// Round 6
// 127.916 us; speedup vs baseline: 1.0283x; 1.0084x over previous
//
#include <hip/hip_runtime.h>
#include <cstdint>

#define NB 8
#define TS 2048
#define NE 1024
#define HD 64
#define MTOT (NB*TS)

typedef float     f4  __attribute__((ext_vector_type(4)));
typedef short     s8v __attribute__((ext_vector_type(8)));
typedef short     s4v __attribute__((ext_vector_type(4)));
typedef int       i4v __attribute__((ext_vector_type(4)));
typedef _Float16  h8  __attribute__((ext_vector_type(8)));

__device__ __forceinline__ short f2bf(float f) {  // RNE
  union { float f; uint32_t u; } x; x.f = f;
  return (short)((x.u + 0x7FFFu + ((x.u >> 16) & 1u)) >> 16);
}

// pack two fp32 -> (bf16(lo) | bf16(hi)<<16) via +0x8000 round + v_perm byte select
__device__ __forceinline__ int pack2(float lo, float hi) {
  union { float f; uint32_t u; } a, b; a.f = lo; b.f = hi;
  return (int)__builtin_amdgcn_perm(b.u + 0x8000u, a.u + 0x8000u, 0x07060302u);
}

// async global->LDS DMA, 16B/lane; lptr wave-uniform, lane i -> lptr + i*16
__device__ __forceinline__ void gl2lds(const void* gptr, void* lptr) {
  auto g = (const __attribute__((address_space(1))) uint32_t*)gptr;
  auto l = (__attribute__((address_space(3))) uint32_t*)lptr;
  __builtin_amdgcn_global_load_lds(g, l, 16, 0, 0);
}

// barrier that keeps N newest vmem ops in flight (AITER-style, never drain unless N=0)
template <int N>
__device__ __forceinline__ void wait_barrier() {
  asm volatile("s_waitcnt vmcnt(%0) lgkmcnt(0)" :: "n"(N) : "memory");
  __builtin_amdgcn_s_barrier();
}

// ---- kernel 0: W fp32 -> bf16 (q-scale folded). wb [192][1024]: 0-63 q, 64-127 k, 128-191 v
__global__ __launch_bounds__(256) void wconv_kernel(
    const float* __restrict__ Wk, const float* __restrict__ Wq, const float* __restrict__ Wv,
    short* __restrict__ wb)
{
  const int idx = (blockIdx.x * 256 + threadIdx.x) * 4;
  const int p = idx >> 16;
  const int off = idx & 65535;
  const float* W = (p == 0) ? Wq : (p == 1) ? Wk : Wv;
  const float s = (p == 0) ? 0.18033688011112042f : 1.0f; // (1/8)*log2(e)
  const float4 v = *(const float4*)&W[off];
  s4v h; h[0] = f2bf(v.x*s); h[1] = f2bf(v.y*s); h[2] = f2bf(v.z*s); h[3] = f2bf(v.w*s);
  *(s4v*)&wb[idx] = h;
}

// ---- kernel 1: fused qkv projection. grid 512 x 256 thr, tile 32 rows x 192 cols,
// wave = 16 rows x 96 cols. LDS exactly 80 KB -> 2 blocks/CU (8 waves/CU).
// x: 4-buf fp32 DMA (3-ahead issue); W: 2-buf bf16 DMA (1-ahead). XOR slot-swizzle.
__global__ __launch_bounds__(256) void proj_kernel(
    const float* __restrict__ x, const short* __restrict__ wb,
    short* __restrict__ qo, short* __restrict__ ko, _Float16* __restrict__ vo)
{
  __shared__ float Xs[4][32][64];    // 32 KB
  __shared__ short Ws[2][192][64];   // 48 KB
  const int tid = threadIdx.x;
  const int wv = tid >> 6, lane = tid & 63, n = lane & 15, quad = lane >> 4;
  const int mg = wv & 1, cg = wv >> 1;
  const int r0 = blockIdx.x * 32;
  const int xrow = lane >> 4, xslot = lane & 15;   // x DMA: 4 rows x 16 slots (16B fp32)
  const int wrow = lane >> 3, wslot = lane & 7;    // W DMA: 8 cols x 8 slots (16B bf16)

  auto dmaX = [&](int c, int buf) {
#pragma unroll
    for (int u = 0; u < 2; ++u) {
      const int R0 = (wv * 2 + u) * 4;
      const int row = R0 + xrow;
      const int gs = (xslot + row) & 15;
      gl2lds(&x[(size_t)(r0 + row) * NE + c * 64 + gs * 4], &Xs[buf][R0][0]);
    }
  };
  auto dmaW = [&](int c, int buf) {
#pragma unroll
    for (int u = 0; u < 6; ++u) {
      const int C0 = (wv * 6 + u) * 8;
      const int col = C0 + wrow;
      const int gs = (wslot + col) & 7;
      gl2lds(&wb[(size_t)col * NE + c * 64 + gs * 8], &Ws[buf][C0][0]);
    }
  };

  const f4 fz = {0.f, 0.f, 0.f, 0.f};
  f4 acc[6] = {fz, fz, fz, fz, fz, fz};

  auto compute = [&](int bw, int bx) {
    s8v a[2];
    const int row = mg * 16 + n;
#pragma unroll
    for (int kc = 0; kc < 2; ++kc) {
      const int u0 = kc * 8 + quad * 2;
      const float* pr = &Xs[bx][row][0];
      const f4 f0 = *(const f4*)(pr + (((u0    ) - row) & 15) * 4);
      const f4 f1 = *(const f4*)(pr + (((u0 + 1) - row) & 15) * 4);
      i4v ai;
      ai[0] = pack2(f0[0], f0[1]); ai[1] = pack2(f0[2], f0[3]);
      ai[2] = pack2(f1[0], f1[1]); ai[3] = pack2(f1[2], f1[3]);
      a[kc] = __builtin_bit_cast(s8v, ai);
    }
#pragma unroll
    for (int nf = 0; nf < 6; ++nf) {
      const int col = cg * 96 + nf * 16 + n;
      const s8v b0 = *(const s8v*)&Ws[bw][col][(((0 + quad) - col) & 7) * 8];
      const s8v b1 = *(const s8v*)&Ws[bw][col][(((4 + quad) - col) & 7) * 8];
      acc[nf] = __builtin_amdgcn_mfma_f32_16x16x32_bf16(a[0], b0, acc[nf], 0, 0, 0);
      acc[nf] = __builtin_amdgcn_mfma_f32_16x16x32_bf16(a[1], b1, acc[nf], 0, 0, 0);
    }
  };

  // prologue: W0 first, then X0..X2 (FIFO: waiting for X0 keeps X1,X2 in flight)
  dmaW(0, 0); dmaX(0, 0); dmaX(1, 1); dmaX(2, 2);
  wait_barrier<4>();

  for (int t = 0; t < 16; ++t) {
    if (t <= 14) dmaW(t + 1, (t + 1) & 1);   // W first (older in FIFO than this iter's X)
    if (t <= 12) dmaX(t + 3, (t + 3) & 3);
    compute(t & 1, t & 3);
    if (t <= 12)      wait_barrier<2>();     // keep X(t+3) flying; X(t+1),W(t+1) landed
    else if (t <= 14) wait_barrier<0>();     // tail
  }

  // epilogue: C row = quad*4+i, col = n (+16*nf)
#pragma unroll
  for (int nf = 0; nf < 6; ++nf) {
    const int gc = cg * 96 + nf * 16;
    const int p = gc >> 6;
    const int rcol = (gc & 63) + n;
#pragma unroll
    for (int i = 0; i < 4; ++i) {
      const int R = r0 + mg * 16 + quad * 4 + i;
      const float av = acc[nf][i];
      if (p == 0)      qo[(size_t)R * HD + rcol] = f2bf(av);
      else if (p == 1) ko[(size_t)R * HD + rcol] = f2bf(av);
      else {
        // V transposed [b][d][t'] + key-order swizzle so attn PV B-frags are single 16B loads
        const int t2 = R & (TS - 1), b = t2 & 31;
        const int pos = (t2 & ~31) | (((b >> 2) & 3) << 3) | (((b >> 4) & 1) << 2) | (b & 3);
        vo[(size_t)(R >> 11) * HD * TS + (size_t)rcol * TS + pos] = (_Float16)av;
      }
    }
  }
}

// ---- kernel 2: attention. grid 256 x 512 thr (8 waves). 64 q/block.
// Waves = 2 q-groups (32 q each) x 4 key-quarters (512 keys = 8 chunks of 64).
// K AND V staged in LDS, 2-buf each: 128 KB, 1 block/CU, 8 waves.
// SINGLE barrier per iteration: prefetch for chunk t+1 is issued at the TOP of iter t
// (the previous iter's wait_barrier lgkmcnt(0) already retired all reads of the target
// buffer -> no WAR hazard), then one vmcnt(0)+barrier at the END. The prefetch has the
// whole compute body (~1300 cyc) to cover ~250 cyc L2-resident latency, so the drain is
// nearly free. Best-measured schedule (R3: 126.7 µs); finer-grained variants (R4 wave-
// private 32q, R5 wave-private eighths) both regressed — this is the sweet spot.
// S^T = K Q^T -> exp2 in-reg -> f16 PV; l via P*ones. 4-way combine in LDS overlay.
__global__ __launch_bounds__(512) void attn_kernel(
    const short* __restrict__ q, const short* __restrict__ k,
    const _Float16* __restrict__ vT, float* __restrict__ out)
{
  __shared__ __align__(16) char smem[131072];  // K[4][2][64][64]s (64KB) | V[4][2][64][64]h (64KB)
  const int tid = threadIdx.x;
  const int wv = tid >> 6, lane = tid & 63, n = lane & 15, quad = lane >> 4;
  const int kq = wv & 3, qg = wv >> 2;         // key-quarter, q-group
  const int batch = blockIdx.x & 7;            // XCD swizzle: batch K/V pinned per XCD L2
  const int qgb = blockIdx.x >> 3;
  const int m0 = batch * TS + qgb * 64;
  const short*    kb = k  + (size_t)batch * TS * HD;
  const _Float16* vb = vT + (size_t)batch * HD * TS;
  const int drow = lane >> 3, dslot = lane & 7;
  const f4 fz = {0.f, 0.f, 0.f, 0.f};

  auto kbuf = [&](int buf) { return (short*)   (smem +         (kq * 2 + buf) * 8192); };
  auto vbuf = [&](int buf) { return (_Float16*)(smem + 65536 + (kq * 2 + buf) * 8192); };

  // stage one 64-key K+V chunk for this quarter; 2 waves (qg 0/1) split rows 4 ways each
  auto dmaKV = [&](int tt, int buf) {
    const int c = kq * 8 + tt;
#pragma unroll
    for (int u = 0; u < 4; ++u) {
      const int K0 = (qg * 4 + u) * 8;
      const int key = K0 + drow;
      const int gs = (dslot + key) & 7;
      gl2lds(&kb[(size_t)(c * 64 + key) * HD + gs * 8], kbuf(buf) + K0 * 64);
    }
#pragma unroll
    for (int u = 0; u < 4; ++u) {
      const int D0 = (qg * 4 + u) * 8;
      const int d = D0 + drow;
      const int gs = (dslot + d) & 7;
      gl2lds(&vb[(size_t)d * TS + c * 64 + gs * 8], vbuf(buf) + D0 * 64);
    }
  };

  s8v qf[2][2];
#pragma unroll
  for (int qh = 0; qh < 2; ++qh)
#pragma unroll
    for (int kc = 0; kc < 2; ++kc)
      qf[qh][kc] = *(const s8v*)&q[(size_t)(m0 + qg * 32 + qh * 16 + n) * HD + kc * 32 + quad * 8];

  f4 o[2][4] = {{fz, fz, fz, fz}, {fz, fz, fz, fz}};
  f4 lD[2] = {fz, fz};
  h8 ones;
#pragma unroll
  for (int j = 0; j < 8; ++j) ones[j] = (_Float16)1.0f;

  dmaKV(0, 0); dmaKV(1, 1);   // 8 ops each
  wait_barrier<8>();          // chunk 0 landed; chunk 1's 8 ops in flight

  for (int t = 0; t < 8; ++t) {
    const int buf = t & 1;

    // prefetch chunk t+1 into the buffer consumed at t-1 (WAR-safe: prior barrier's
    // lgkmcnt(0) retired all its readers). t=0's chunk 1 came from the prologue.
    if (t >= 1 && t <= 6) dmaKV(t + 1, (t + 1) & 1);

    const short*    ks = kbuf(buf);
    const _Float16* vs = vbuf(buf);

    // QK^T: per key-fragment, feed both q-groups immediately (short kf live range)
    f4 st[2][4];
#pragma unroll
    for (int f = 0; f < 4; ++f) {
      const int key = f * 16 + n;
      const s8v k0 = *(const s8v*)&ks[key * 64 + (((0 + quad) - key) & 7) * 8];
      const s8v k1 = *(const s8v*)&ks[key * 64 + (((4 + quad) - key) & 7) * 8];
#pragma unroll
      for (int qh = 0; qh < 2; ++qh) {
        st[qh][f] = __builtin_amdgcn_mfma_f32_16x16x32_bf16(k0, qf[qh][0], fz, 0, 0, 0);
        st[qh][f] = __builtin_amdgcn_mfma_f32_16x16x32_bf16(k1, qf[qh][1], st[qh][f], 0, 0, 0);
      }
    }

    h8 pa[2][2];
#pragma unroll
    for (int qh = 0; qh < 2; ++qh)
#pragma unroll
      for (int pr = 0; pr < 2; ++pr)
#pragma unroll
        for (int hf = 0; hf < 2; ++hf)
#pragma unroll
          for (int i = 0; i < 4; ++i)
            pa[qh][pr][hf * 4 + i] = (_Float16)__builtin_amdgcn_exp2f(st[qh][pr * 2 + hf][i]);

#pragma unroll
    for (int pr = 0; pr < 2; ++pr) {
#pragma unroll
      for (int qh = 0; qh < 2; ++qh)
        lD[qh] = __builtin_amdgcn_mfma_f32_16x16x32_f16(pa[qh][pr], ones, lD[qh], 0, 0, 0);
#pragma unroll
      for (int g = 0; g < 4; ++g) {
        const int d = g * 16 + n;
        const h8 vf = *(const h8*)&vs[d * 64 + (((pr * 4 + quad) - d) & 7) * 8];
#pragma unroll
        for (int qh = 0; qh < 2; ++qh)
          o[qh][g] = __builtin_amdgcn_mfma_f32_16x16x32_f16(pa[qh][pr], vf, o[qh][g], 0, 0, 0);
      }
    }

    // single sync point per iteration: chunk t+1 fully landed (it had the whole
    // compute body of cover); nothing else outstanding -> vmcnt(0) is cheap here.
    if (t <= 6) wait_barrier<0>();
  }

  __syncthreads();   // all waves done with K/V LDS before overlay

  float* o_c = (float*)smem;              // [4 kq][64 q][68]  (68 pad: 2-way banks, 16B-aligned)
  float* l_c = (float*)(smem + 69632);    // [4 kq][64 q]
  if (n == 0)
#pragma unroll
    for (int qh = 0; qh < 2; ++qh)
#pragma unroll
      for (int i = 0; i < 4; ++i)
        l_c[kq * 64 + qg * 32 + qh * 16 + quad * 4 + i] = lD[qh][i];
#pragma unroll
  for (int qh = 0; qh < 2; ++qh)
#pragma unroll
    for (int g = 0; g < 4; ++g)
#pragma unroll
      for (int i = 0; i < 4; ++i)
        o_c[kq * 4352 + (qg * 32 + qh * 16 + quad * 4 + i) * 68 + g * 16 + n] = o[qh][g][i];
  __syncthreads();

  // combine quarters: 1024 output-groups (64 q x 16 d4), 512 thr x 2 reps
#pragma unroll
  for (int rep = 0; rep < 2; ++rep) {
    const int idx = tid + rep * 512;
    const int qr = idx >> 4, d4 = (idx & 15) * 4;
    float L = 0.f;
    f4 r = fz;
#pragma unroll
    for (int c2 = 0; c2 < 4; ++c2) {
      L += l_c[c2 * 64 + qr];
      r += *(const f4*)&o_c[c2 * 4352 + qr * 68 + d4];
    }
    const float inv = 1.0f / L;
    r[0] *= inv; r[1] *= inv; r[2] *= inv; r[3] *= inv;
    *(f4*)&out[(size_t)(m0 + qr) * HD + d4] = r;
  }
}

extern "C" void kernel_launch(void* const* d_in, const int* in_sizes, int n_in,
                              void* d_out, int out_size, void* d_ws, size_t ws_size,
                              hipStream_t stream) {
  const float* x  = (const float*)d_in[0];
  const float* Wk = (const float*)d_in[1];
  const float* Wq = (const float*)d_in[2];
  const float* Wv = (const float*)d_in[3];
  float* out = (float*)d_out;

  short* qb = (short*)d_ws;                           // [MTOT][64] bf16 (pre-scaled)
  short* kb = qb + (size_t)MTOT * HD;                 // [MTOT][64] bf16
  _Float16* vb = (_Float16*)(kb + (size_t)MTOT * HD); // [NB][64][TS] f16, key-swizzled
  short* wb = (short*)(vb + (size_t)NB * HD * TS);    // [192][1024] bf16 weights

  wconv_kernel<<<192, 256, 0, stream>>>(Wk, Wq, Wv, wb);
  proj_kernel<<<MTOT / 32, 256, 0, stream>>>(x, wb, qb, kb, vb);
  attn_kernel<<<MTOT / 64, 512, 0, stream>>>(qb, kb, vb, out);
}